// Round 1
// baseline (2131.309 us; speedup 1.0000x reference)
//
#include <hip/hip_runtime.h>
#include <cmath>

typedef unsigned short u16;
typedef unsigned int u32;
typedef __attribute__((ext_vector_type(8))) short short8;
typedef __attribute__((ext_vector_type(4))) float f32x4;

#define B_    64
#define NV    385
#define CDIM  768
#define NQ    321
#define SFL   256
#define NH    12
#define HD    64
#define MQ    (B_*NV)   /* 24640 */
#define MP    (B_*NQ)   /* 20544 */
#define MD    (B_*SFL)  /* 16384 */
#define SCALE_ 0.125f
#define EPS_   1e-6f

__device__ __forceinline__ u16 f2b(float f) {
  u32 x = __float_as_uint(f);
  return (u16)((x + 0x7FFFu + ((x >> 16) & 1u)) >> 16);
}

// ---------------- fp32 -> bf16 convert (vectorized) ----------------
__global__ void k_convert4(const float4* __restrict__ in, ushort4* __restrict__ out, int n4) {
  int i = blockIdx.x * blockDim.x + threadIdx.x;
  if (i < n4) {
    float4 v = in[i];
    ushort4 o;
    o.x = f2b(v.x); o.y = f2b(v.y); o.z = f2b(v.z); o.w = f2b(v.w);
    out[i] = o;
  }
}

// ---------------- tgt_rep = mean over x[:, 65:129, :] ----------------
__global__ void k_tgt(const float* __restrict__ x, float* __restrict__ tgt) {
  int b = blockIdx.x, c = threadIdx.x; // block = 768 threads
  float s = 0.f;
  for (int j = 0; j < 64; ++j) s += x[((size_t)(b*NV + 65 + j))*CDIM + c];
  tgt[b*CDIM + c] = s * (1.f/64.f);
}

// ---------------- bf16 wave-GEMM: C[m,n] = sum_k A[m,k]*W[n,k] + bias[n] ----------------
// grid: (N/16, M/16), block: 64 (one wave). mode 0 -> bf16 out, 1 -> f32 out.
__global__ __launch_bounds__(64) void k_gemm_bf16(const u16* __restrict__ A, const u16* __restrict__ W,
                                                  const float* __restrict__ bias,
                                                  u16* __restrict__ Cb, float* __restrict__ Cf,
                                                  int M, int N, int K, int mode) {
  int lane = threadIdx.x;
  int n0 = blockIdx.x * 16, m0 = blockIdx.y * 16;
  const u16* Ap = A + (size_t)(m0 + (lane & 15)) * K + ((lane >> 4) * 8);
  const u16* Wp = W + (size_t)(n0 + (lane & 15)) * K + ((lane >> 4) * 8);
  f32x4 acc = {0.f, 0.f, 0.f, 0.f};
  for (int k = 0; k < K; k += 32) {
    short8 a = *(const short8*)(Ap + k);
    short8 w = *(const short8*)(Wp + k);
    acc = __builtin_amdgcn_mfma_f32_16x16x32_bf16(a, w, acc, 0, 0, 0);
  }
  int col = lane & 15, rq = (lane >> 4) * 4;
  float bv = bias ? bias[n0 + col] : 0.f;
#pragma unroll
  for (int i = 0; i < 4; ++i) {
    float v = acc[i] + bv;
    size_t off = (size_t)(m0 + rq + i) * N + (n0 + col);
    if (mode == 0) Cb[off] = f2b(v);
    else           Cf[off] = v;
  }
}

// ---------------- fp32 tiled GEMM + exact GELU (decision path must stay fp32) ----------------
__device__ __forceinline__ float gelu_exact(float x) {
  return 0.5f * x * (1.f + erff(x * 0.70710678118654752f));
}
// grid: (N/64, M/64), block (16,16). gather=1: A row m -> [x[b,129+s,k] | tgt[b,k-768]]
__global__ __launch_bounds__(256) void k_gemm_f32(const float* __restrict__ A,
                                                  const float* __restrict__ x, const float* __restrict__ tgt,
                                                  const float* __restrict__ W, const float* __restrict__ bias,
                                                  float* __restrict__ Cc, int M, int N, int K, int gather) {
  __shared__ __align__(16) float As[16][72];
  __shared__ __align__(16) float Ws[16][72];
  int tx = threadIdx.x, ty = threadIdx.y;
  int tid = ty * 16 + tx;
  int n0 = blockIdx.x * 64, m0 = blockIdx.y * 64;
  float acc[4][4] = {};
  for (int k0 = 0; k0 < K; k0 += 16) {
    int mm = tid >> 2, kk = (tid & 3) * 4;
    float4 v;
    if (gather) {
      int m = m0 + mm;
      int b = m >> 8, s2 = m & 255;
      int kg = k0 + kk;
      if (kg < 768) v = *(const float4*)(x + ((size_t)(b*NV + 129 + s2))*CDIM + kg);
      else          v = *(const float4*)(tgt + (size_t)b*CDIM + (kg - 768));
    } else {
      v = *(const float4*)(A + (size_t)(m0 + mm) * K + k0 + kk);
    }
    As[kk+0][mm] = v.x; As[kk+1][mm] = v.y; As[kk+2][mm] = v.z; As[kk+3][mm] = v.w;
    float4 wv = *(const float4*)(W + (size_t)(n0 + mm) * K + k0 + kk);
    Ws[kk+0][mm] = wv.x; Ws[kk+1][mm] = wv.y; Ws[kk+2][mm] = wv.z; Ws[kk+3][mm] = wv.w;
    __syncthreads();
#pragma unroll
    for (int k2 = 0; k2 < 16; ++k2) {
      float4 av = *(const float4*)&As[k2][ty*4];
      float4 wv2 = *(const float4*)&Ws[k2][tx*4];
      float a_[4] = {av.x, av.y, av.z, av.w};
      float w_[4] = {wv2.x, wv2.y, wv2.z, wv2.w};
#pragma unroll
      for (int i = 0; i < 4; ++i)
#pragma unroll
        for (int j = 0; j < 4; ++j) acc[i][j] += a_[i] * w_[j];
    }
    __syncthreads();
  }
#pragma unroll
  for (int i = 0; i < 4; ++i)
#pragma unroll
    for (int j = 0; j < 4; ++j) {
      int n = n0 + tx*4 + j;
      Cc[(size_t)(m0 + ty*4 + i) * N + n] = gelu_exact(acc[i][j] + bias[n]);
    }
}

// ---------------- decision: argmax of (h2 @ dp3_w.T + dp3_b), fp32 ----------------
__global__ void k_decision(const float* __restrict__ h2, const float* __restrict__ w3,
                           const float* __restrict__ b3, float* __restrict__ sdec) {
  int r = blockIdx.x * blockDim.x + threadIdx.x; // 16384 rows
  const float* hp = h2 + (size_t)r * 192;
  float l0 = b3[0], l1 = b3[1];
  for (int k = 0; k < 192; ++k) { float h = hp[k]; l0 += h * w3[k]; l1 += h * w3[192 + k]; }
  sdec[r] = (l1 > l0) ? 1.f : 0.f; // jnp.argmax ties -> 0
}

// ---------------- attention: one block (256 thr / 4 waves) per (b, h) ----------------
// qkvb layout: [b*385+pos][3*768] bf16 ; q cols 0..767, k cols 768..1535, v cols 1536..2303
__global__ __launch_bounds__(256) void k_attn(const u16* __restrict__ qkvb, const float* __restrict__ sdec,
                                              u16* __restrict__ O) {
  __shared__ __align__(16) u16 vsT[64][424];   // V^T: [d][key], stride 424 (2-way bank alias only)
  __shared__ float sd[256];
  __shared__ __align__(16) u16 pst[4][16][40]; // per-wave P staging, 16x32 used, stride 40
  int b = blockIdx.x, h = blockIdx.y;
  int tid = threadIdx.x;
  int wave = tid >> 6, lane = tid & 63;
  int quad = lane >> 4, col = lane & 15;

  sd[tid] = sdec[b*SFL + tid];
  // zero pad columns 385..423 (LDS is uninitialized; pad cols feed PV chunk 12 B-frags)
  for (int i = tid; i < 64*39; i += 256) {
    int d = i / 39, c = 385 + (i - d*39);
    vsT[d][c] = 0;
  }
  // stage V transposed
  for (int idx = tid; idx < NV*8; idx += 256) {
    int n = idx >> 3, seg = idx & 7;
    const u16* src = qkvb + ((size_t)(b*NV + n))*2304 + 1536 + h*HD + seg*8;
    int d0 = seg*8;
#pragma unroll
    for (int j = 0; j < 8; ++j) vsT[d0 + j][n] = src[j];
  }
  __syncthreads();

  for (int t = wave; t < 21; t += 4) { // 21 q-tiles of 16 rows (321 rows, last padded)
    // ---- A-frags (Q) ----
    int qn_a = t*16 + col;
    int pos = (qn_a == 0) ? 0 : (min(qn_a, 320) + 64);
    const u16* qp = qkvb + ((size_t)(b*NV + pos))*2304 + h*HD + quad*8;
    short8 aq0 = *(const short8*)(qp);
    short8 aq1 = *(const short8*)(qp + 32);

    // ---- QK^T: 25 key tiles of 16, K=64 (2 MFMA each) ----
    f32x4 acc[25];
    f32x4 z4 = {0.f, 0.f, 0.f, 0.f};
#pragma unroll
    for (int kt = 0; kt < 25; ++kt) acc[kt] = z4;
#pragma unroll
    for (int kt = 0; kt < 25; ++kt) {
      int key = min(kt*16 + col, 384);
      const u16* kp = qkvb + ((size_t)(b*NV + key))*2304 + 768 + h*HD + quad*8;
      short8 b0 = *(const short8*)(kp);
      short8 b1 = *(const short8*)(kp + 32);
      acc[kt] = __builtin_amdgcn_mfma_f32_16x16x32_bf16(aq0, b0, acc[kt], 0, 0, 0);
      acc[kt] = __builtin_amdgcn_mfma_f32_16x16x32_bf16(aq1, b1, acc[kt], 0, 0, 0);
    }

    // ---- softmax (reference-exact: pre-mask row max; (a+eps/321)/(sum+eps)) ----
    float inv[4];
#pragma unroll
    for (int i = 0; i < 4; ++i) {
      int qn = t*16 + quad*4 + i;
      bool rowTpl = (qn >= 1 && qn <= 64);
      bool rowSearch = (qn >= 65);
      float sdq = rowSearch ? sd[min(qn - 65, 255)] : 1.f;
      float mx = -1e30f;
#pragma unroll
      for (int kt = 0; kt < 25; ++kt) {
        int key = kt*16 + col;
        if (key <= 384) mx = fmaxf(mx, acc[kt][i]);
      }
#pragma unroll
      for (int m2 = 1; m2 <= 8; m2 <<= 1) mx = fmaxf(mx, __shfl_xor(mx, m2, 64));
      mx *= SCALE_;
      float sum = 0.f;
#pragma unroll
      for (int kt = 0; kt < 25; ++kt) {
        int key = kt*16 + col;
        float a = 0.f;
        if (key <= 384) {
          float msk = 1.f;
          if (rowTpl && key >= 129) msk = sd[key - 129];
          if (rowSearch && key >= 1 && key <= 128) msk = sdq;
          a = __expf(acc[kt][i] * SCALE_ - mx) * msk;
        }
        acc[kt][i] = a;
        sum += a;
      }
#pragma unroll
      for (int m2 = 1; m2 <= 8; m2 <<= 1) sum += __shfl_xor(sum, m2, 64);
      inv[i] = 1.f / (sum + EPS_);
    }

    // ---- PV: 13 chunks of 32 keys; P -> LDS (A-layout) -> MFMA with vsT ----
    f32x4 oc[4];
#pragma unroll
    for (int nt = 0; nt < 4; ++nt) oc[nt] = z4;
    const float epsn = EPS_ / 321.f;
#pragma unroll
    for (int kc = 0; kc < 13; ++kc) {
#pragma unroll
      for (int half = 0; half < 2; ++half) {
        int kt = kc*2 + half;
        if (kt < 25) {
#pragma unroll
          for (int i = 0; i < 4; ++i) {
            int key = kt*16 + col;
            float w = (key <= 384) ? (acc[kt][i] + epsn) * inv[i] : 0.f;
            pst[wave][quad*4 + i][half*16 + col] = f2b(w);
          }
        } else {
#pragma unroll
          for (int i = 0; i < 4; ++i) pst[wave][quad*4 + i][half*16 + col] = 0;
        }
      }
      short8 pa = *(const short8*)&pst[wave][col][quad*8];
#pragma unroll
      for (int nt = 0; nt < 4; ++nt) {
        short8 bv = *(const short8*)&vsT[nt*16 + col][kc*32 + quad*8];
        oc[nt] = __builtin_amdgcn_mfma_f32_16x16x32_bf16(pa, bv, oc[nt], 0, 0, 0);
      }
    }

    // ---- store O[b, qn, h*64 + d] ----
#pragma unroll
    for (int nt = 0; nt < 4; ++nt)
#pragma unroll
      for (int i = 0; i < 4; ++i) {
        int qn = t*16 + quad*4 + i;
        if (qn <= 320)
          O[((size_t)(b*NQ + qn))*CDIM + h*HD + nt*16 + col] = f2b(oc[nt][i]);
      }
  }
}

extern "C" void kernel_launch(void* const* d_in, const int* in_sizes, int n_in,
                              void* d_out, int out_size, void* d_ws, size_t ws_size,
                              hipStream_t stream) {
  const float* x      = (const float*)d_in[0];
  const float* qkv_w  = (const float*)d_in[2];
  const float* qkv_b  = (const float*)d_in[3];
  const float* proj_w = (const float*)d_in[4];
  const float* proj_b = (const float*)d_in[5];
  const float* dp1_w  = (const float*)d_in[6];
  const float* dp1_b  = (const float*)d_in[7];
  const float* dp2_w  = (const float*)d_in[8];
  const float* dp2_b  = (const float*)d_in[9];
  const float* dp3_w  = (const float*)d_in[10];
  const float* dp3_b  = (const float*)d_in[11];
  float* out = (float*)d_out;

  char* ws = (char*)d_ws;
  size_t off = 0;
  auto alloc = [&](size_t bytes) -> void* {
    void* p = ws + off;
    off += (bytes + 255) & ~(size_t)255;
    return p;
  };
  u16*  xb      = (u16*)alloc((size_t)MQ * CDIM * 2);       // 37.8 MB
  u16*  qkv_wb  = (u16*)alloc((size_t)2304 * CDIM * 2);     // 3.5 MB
  u16*  proj_wb = (u16*)alloc((size_t)CDIM * CDIM * 2);     // 1.2 MB
  u16*  qkvb    = (u16*)alloc((size_t)MQ * 2304 * 2);       // 113.5 MB
  u16*  Obuf    = (u16*)alloc((size_t)MP * CDIM * 2);       // 31.6 MB
  float* tgt    = (float*)alloc((size_t)B_ * CDIM * 4);
  float* h1     = (float*)alloc((size_t)MD * 384 * 4);      // 25.2 MB
  float* h2     = (float*)alloc((size_t)MD * 192 * 4);      // 12.6 MB
  float* sdec   = (float*)alloc((size_t)MD * 4);
  // total ~226 MB

  // converts
  {
    int n4 = MQ * CDIM / 4;
    k_convert4<<<dim3((n4 + 255)/256), dim3(256), 0, stream>>>((const float4*)x, (ushort4*)xb, n4);
  }
  {
    int n4 = 2304 * CDIM / 4;
    k_convert4<<<dim3((n4 + 255)/256), dim3(256), 0, stream>>>((const float4*)qkv_w, (ushort4*)qkv_wb, n4);
  }
  {
    int n4 = CDIM * CDIM / 4;
    k_convert4<<<dim3((n4 + 255)/256), dim3(256), 0, stream>>>((const float4*)proj_w, (ushort4*)proj_wb, n4);
  }
  k_tgt<<<dim3(B_), dim3(CDIM), 0, stream>>>(x, tgt);

  // qkv = x @ qkv_w.T + qkv_b  (bf16 out)
  k_gemm_bf16<<<dim3(2304/16, MQ/16), dim3(64), 0, stream>>>(xb, qkv_wb, qkv_b, qkvb, (float*)nullptr,
                                                             MQ, 2304, CDIM, 0);
  // decision path (fp32)
  k_gemm_f32<<<dim3(384/64, MD/64), dim3(16,16), 0, stream>>>(nullptr, x, tgt, dp1_w, dp1_b, h1,
                                                              MD, 384, 1536, 1);
  k_gemm_f32<<<dim3(192/64, MD/64), dim3(16,16), 0, stream>>>(h1, nullptr, nullptr, dp2_w, dp2_b, h2,
                                                              MD, 192, 384, 0);
  k_decision<<<dim3(MD/256), dim3(256), 0, stream>>>(h2, dp3_w, dp3_b, sdec);

  // attention
  k_attn<<<dim3(B_, NH), dim3(256), 0, stream>>>(qkvb, sdec, Obuf);

  // out = O @ proj_w.T + proj_b (fp32 out)
  k_gemm_bf16<<<dim3(CDIM/16, MP/16), dim3(64), 0, stream>>>(Obuf, proj_wb, proj_b, (u16*)nullptr, out,
                                                             MP, CDIM, CDIM, 1);
}

// Round 2
// 951.714 us; speedup vs baseline: 2.2394x; 2.2394x over previous
//
#include <hip/hip_runtime.h>
#include <cmath>

typedef unsigned short u16;
typedef unsigned int u32;
typedef __attribute__((ext_vector_type(8))) short short8;
typedef __attribute__((ext_vector_type(4))) float f32x4;

#define B_    64
#define NV    385
#define CDIM  768
#define NQ    321
#define SFL   256
#define NH    12
#define HD    64
#define MQ    (B_*NV)   /* 24640 */
#define MP    (B_*NQ)   /* 20544 */
#define MD    (B_*SFL)  /* 16384 */
#define SCALE_ 0.125f
#define EPS_   1e-6f

__device__ __forceinline__ u16 f2b(float f) {
  u32 x = __float_as_uint(f);
  return (u16)((x + 0x7FFFu + ((x >> 16) & 1u)) >> 16);
}

__device__ __forceinline__ void gload_lds16(const void* g, void* l) {
  __builtin_amdgcn_global_load_lds(
      (const __attribute__((address_space(1))) u32*)g,
      (__attribute__((address_space(3))) u32*)l,
      16, 0, 0);
}

// ---------------- fp32 -> bf16 convert (vectorized) ----------------
__global__ void k_convert4(const float4* __restrict__ in, ushort4* __restrict__ out, int n4) {
  int i = blockIdx.x * blockDim.x + threadIdx.x;
  if (i < n4) {
    float4 v = in[i];
    ushort4 o;
    o.x = f2b(v.x); o.y = f2b(v.y); o.z = f2b(v.z); o.w = f2b(v.w);
    out[i] = o;
  }
}

// ---------------- tgt_rep = mean over x[:, 65:129, :] ----------------
__global__ void k_tgt(const float* __restrict__ x, float* __restrict__ tgt) {
  int b = blockIdx.x, c = threadIdx.x; // block = 768 threads
  float s = 0.f;
  for (int j = 0; j < 64; ++j) s += x[((size_t)(b*NV + 65 + j))*CDIM + c];
  tgt[b*CDIM + c] = s * (1.f/64.f);
}

// ---------------- m97-style 128x128 bf16 MFMA GEMM ----------------
// C[m,n] = sum_k A[m,k]*W[n,k] + bias[n]. grid (N/128, ceil(M/128)), block 256.
// Single-buffered LDS staged via global_load_lds width=16 (wave-uniform base + lane*16).
// mode 0 -> bf16 out, 1 -> f32 out. N must be multiple of 128; M edge rows clamped/guarded.
__global__ __launch_bounds__(256) void k_gemm128(const u16* __restrict__ A, const u16* __restrict__ W,
                                                 const float* __restrict__ bias,
                                                 u16* __restrict__ Cb, float* __restrict__ Cf,
                                                 int M, int N, int K, int mode) {
  __shared__ __align__(16) u16 As[128*32];   // [row][k], contiguous (global_load_lds: no padding)
  __shared__ __align__(16) u16 Ws[128*32];
  int tid = threadIdx.x;
  int wave = tid >> 6, lane = tid & 63;
  int quad = lane >> 4, col = lane & 15;
  int m0 = blockIdx.y * 128, n0 = blockIdx.x * 128;

  // staging: chunk c = it*256 + tid; row = c>>2, col8 = (c&3)*8 (16B per chunk)
  int c0 = tid, c1 = 256 + tid;
  int ra0 = min(m0 + (c0 >> 2), M - 1), ra1 = min(m0 + (c1 >> 2), M - 1);
  int rb0 = n0 + (c0 >> 2),             rb1 = n0 + (c1 >> 2);
  const u16* pa0 = A + (size_t)ra0 * K + (c0 & 3) * 8;
  const u16* pa1 = A + (size_t)ra1 * K + (c1 & 3) * 8;
  const u16* pb0 = W + (size_t)rb0 * K + (c0 & 3) * 8;
  const u16* pb1 = W + (size_t)rb1 * K + (c1 & 3) * 8;
  // wave-uniform LDS bases (lane0's chunk); HW adds lane*16
  u16* la0 = &As[(wave * 64) * 8];
  u16* la1 = &As[(256 + wave * 64) * 8];
  u16* lb0 = &Ws[(wave * 64) * 8];
  u16* lb1 = &Ws[(256 + wave * 64) * 8];

  int wm = (wave >> 1) * 64, wn = (wave & 1) * 64;
  f32x4 acc[4][4];
  f32x4 z4 = {0.f, 0.f, 0.f, 0.f};
#pragma unroll
  for (int i = 0; i < 4; ++i)
#pragma unroll
    for (int j = 0; j < 4; ++j) acc[i][j] = z4;

  for (int k0 = 0; k0 < K; k0 += 32) {
    gload_lds16(pa0, la0); gload_lds16(pa1, la1);
    gload_lds16(pb0, lb0); gload_lds16(pb1, lb1);
    pa0 += 32; pa1 += 32; pb0 += 32; pb1 += 32;
    __syncthreads();  // vmcnt(0) drain + barrier

    short8 af[4], bf[4];
#pragma unroll
    for (int i = 0; i < 4; ++i) af[i] = *(const short8*)&As[(wm + i*16 + col) * 32 + quad * 8];
#pragma unroll
    for (int j = 0; j < 4; ++j) bf[j] = *(const short8*)&Ws[(wn + j*16 + col) * 32 + quad * 8];
#pragma unroll
    for (int i = 0; i < 4; ++i)
#pragma unroll
      for (int j = 0; j < 4; ++j)
        acc[i][j] = __builtin_amdgcn_mfma_f32_16x16x32_bf16(af[i], bf[j], acc[i][j], 0, 0, 0);
    __syncthreads();  // compute done before next overwrite
  }

  // epilogue: C/D layout col=lane&15, row=quad*4+reg
#pragma unroll
  for (int j = 0; j < 4; ++j) {
    int cc = n0 + wn + j*16 + col;
    float bv = bias ? bias[cc] : 0.f;
#pragma unroll
    for (int i = 0; i < 4; ++i) {
      int r = m0 + wm + i*16 + quad*4;
#pragma unroll
      for (int ii = 0; ii < 4; ++ii) {
        if (r + ii < M) {
          float v = acc[i][j][ii] + bv;
          size_t off = (size_t)(r + ii) * N + cc;
          if (mode == 0) Cb[off] = f2b(v);
          else           Cf[off] = v;
        }
      }
    }
  }
}

// ---------------- fp32 tiled GEMM + exact GELU (decision path must stay fp32) ----------------
__device__ __forceinline__ float gelu_exact(float x) {
  return 0.5f * x * (1.f + erff(x * 0.70710678118654752f));
}
// grid: (N/64, M/64), block (16,16). gather=1: A row m -> [x[b,129+s,k] | tgt[b,k-768]]
__global__ __launch_bounds__(256) void k_gemm_f32(const float* __restrict__ A,
                                                  const float* __restrict__ x, const float* __restrict__ tgt,
                                                  const float* __restrict__ W, const float* __restrict__ bias,
                                                  float* __restrict__ Cc, int M, int N, int K, int gather) {
  __shared__ __align__(16) float As[16][72];
  __shared__ __align__(16) float Ws[16][72];
  int tx = threadIdx.x, ty = threadIdx.y;
  int tid = ty * 16 + tx;
  int n0 = blockIdx.x * 64, m0 = blockIdx.y * 64;
  float acc[4][4] = {};
  for (int k0 = 0; k0 < K; k0 += 16) {
    int mm = tid >> 2, kk = (tid & 3) * 4;
    float4 v;
    if (gather) {
      int m = m0 + mm;
      int b = m >> 8, s2 = m & 255;
      int kg = k0 + kk;
      if (kg < 768) v = *(const float4*)(x + ((size_t)(b*NV + 129 + s2))*CDIM + kg);
      else          v = *(const float4*)(tgt + (size_t)b*CDIM + (kg - 768));
    } else {
      v = *(const float4*)(A + (size_t)(m0 + mm) * K + k0 + kk);
    }
    As[kk+0][mm] = v.x; As[kk+1][mm] = v.y; As[kk+2][mm] = v.z; As[kk+3][mm] = v.w;
    float4 wv = *(const float4*)(W + (size_t)(n0 + mm) * K + k0 + kk);
    Ws[kk+0][mm] = wv.x; Ws[kk+1][mm] = wv.y; Ws[kk+2][mm] = wv.z; Ws[kk+3][mm] = wv.w;
    __syncthreads();
#pragma unroll
    for (int k2 = 0; k2 < 16; ++k2) {
      float4 av = *(const float4*)&As[k2][ty*4];
      float4 wv2 = *(const float4*)&Ws[k2][tx*4];
      float a_[4] = {av.x, av.y, av.z, av.w};
      float w_[4] = {wv2.x, wv2.y, wv2.z, wv2.w};
#pragma unroll
      for (int i = 0; i < 4; ++i)
#pragma unroll
        for (int j = 0; j < 4; ++j) acc[i][j] += a_[i] * w_[j];
    }
    __syncthreads();
  }
#pragma unroll
  for (int i = 0; i < 4; ++i)
#pragma unroll
    for (int j = 0; j < 4; ++j) {
      int n = n0 + tx*4 + j;
      Cc[(size_t)(m0 + ty*4 + i) * N + n] = gelu_exact(acc[i][j] + bias[n]);
    }
}

// ---------------- decision: argmax of (h2 @ dp3_w.T + dp3_b), fp32 ----------------
__global__ void k_decision(const float* __restrict__ h2, const float* __restrict__ w3,
                           const float* __restrict__ b3, float* __restrict__ sdec) {
  int r = blockIdx.x * blockDim.x + threadIdx.x; // 16384 rows
  const float* hp = h2 + (size_t)r * 192;
  float l0 = b3[0], l1 = b3[1];
  for (int k = 0; k < 192; ++k) { float h = hp[k]; l0 += h * w3[k]; l1 += h * w3[192 + k]; }
  sdec[r] = (l1 > l0) ? 1.f : 0.f; // jnp.argmax ties -> 0
}

// ---------------- attention: one block (256 thr / 4 waves) per (b, h) ----------------
// qkvb layout: [b*385+pos][3*768] bf16 ; q cols 0..767, k cols 768..1535, v cols 1536..2303
__global__ __launch_bounds__(256) void k_attn(const u16* __restrict__ qkvb, const float* __restrict__ sdec,
                                              u16* __restrict__ O) {
  __shared__ __align__(16) u16 vsT[64][424];   // V^T: [d][key], stride 424 (2-way bank alias only)
  __shared__ float sd[256];
  __shared__ __align__(16) u16 pst[4][16][40]; // per-wave P staging, 16x32 used, stride 40
  int b = blockIdx.x, h = blockIdx.y;
  int tid = threadIdx.x;
  int wave = tid >> 6, lane = tid & 63;
  int quad = lane >> 4, col = lane & 15;

  sd[tid] = sdec[b*SFL + tid];
  // zero pad columns 385..423 (LDS is uninitialized; pad cols feed PV chunk 12 B-frags)
  for (int i = tid; i < 64*39; i += 256) {
    int d = i / 39, c = 385 + (i - d*39);
    vsT[d][c] = 0;
  }
  // stage V transposed
  for (int idx = tid; idx < NV*8; idx += 256) {
    int n = idx >> 3, seg = idx & 7;
    const u16* src = qkvb + ((size_t)(b*NV + n))*2304 + 1536 + h*HD + seg*8;
    int d0 = seg*8;
#pragma unroll
    for (int j = 0; j < 8; ++j) vsT[d0 + j][n] = src[j];
  }
  __syncthreads();

  for (int t = wave; t < 21; t += 4) { // 21 q-tiles of 16 rows (321 rows, last padded)
    // ---- A-frags (Q) ----
    int qn_a = t*16 + col;
    int pos = (qn_a == 0) ? 0 : (min(qn_a, 320) + 64);
    const u16* qp = qkvb + ((size_t)(b*NV + pos))*2304 + h*HD + quad*8;
    short8 aq0 = *(const short8*)(qp);
    short8 aq1 = *(const short8*)(qp + 32);

    // ---- QK^T: 25 key tiles of 16, K=64 (2 MFMA each) ----
    f32x4 acc[25];
    f32x4 z4 = {0.f, 0.f, 0.f, 0.f};
#pragma unroll
    for (int kt = 0; kt < 25; ++kt) acc[kt] = z4;
#pragma unroll
    for (int kt = 0; kt < 25; ++kt) {
      int key = min(kt*16 + col, 384);
      const u16* kp = qkvb + ((size_t)(b*NV + key))*2304 + 768 + h*HD + quad*8;
      short8 b0 = *(const short8*)(kp);
      short8 b1 = *(const short8*)(kp + 32);
      acc[kt] = __builtin_amdgcn_mfma_f32_16x16x32_bf16(aq0, b0, acc[kt], 0, 0, 0);
      acc[kt] = __builtin_amdgcn_mfma_f32_16x16x32_bf16(aq1, b1, acc[kt], 0, 0, 0);
    }

    // ---- softmax (reference-exact: pre-mask row max; (a+eps/321)/(sum+eps)) ----
    float inv[4];
#pragma unroll
    for (int i = 0; i < 4; ++i) {
      int qn = t*16 + quad*4 + i;
      bool rowTpl = (qn >= 1 && qn <= 64);
      bool rowSearch = (qn >= 65);
      float sdq = rowSearch ? sd[min(qn - 65, 255)] : 1.f;
      float mx = -1e30f;
#pragma unroll
      for (int kt = 0; kt < 25; ++kt) {
        int key = kt*16 + col;
        if (key <= 384) mx = fmaxf(mx, acc[kt][i]);
      }
#pragma unroll
      for (int m2 = 1; m2 <= 8; m2 <<= 1) mx = fmaxf(mx, __shfl_xor(mx, m2, 64));
      mx *= SCALE_;
      float sum = 0.f;
#pragma unroll
      for (int kt = 0; kt < 25; ++kt) {
        int key = kt*16 + col;
        float a = 0.f;
        if (key <= 384) {
          float msk = 1.f;
          if (rowTpl && key >= 129) msk = sd[key - 129];
          if (rowSearch && key >= 1 && key <= 128) msk = sdq;
          a = __expf(acc[kt][i] * SCALE_ - mx) * msk;
        }
        acc[kt][i] = a;
        sum += a;
      }
#pragma unroll
      for (int m2 = 1; m2 <= 8; m2 <<= 1) sum += __shfl_xor(sum, m2, 64);
      inv[i] = 1.f / (sum + EPS_);
    }

    // ---- PV: 13 chunks of 32 keys; P -> LDS (A-layout) -> MFMA with vsT ----
    f32x4 oc[4];
#pragma unroll
    for (int nt = 0; nt < 4; ++nt) oc[nt] = z4;
    const float epsn = EPS_ / 321.f;
#pragma unroll
    for (int kc = 0; kc < 13; ++kc) {
#pragma unroll
      for (int half = 0; half < 2; ++half) {
        int kt = kc*2 + half;
        if (kt < 25) {
#pragma unroll
          for (int i = 0; i < 4; ++i) {
            int key = kt*16 + col;
            float w = (key <= 384) ? (acc[kt][i] + epsn) * inv[i] : 0.f;
            pst[wave][quad*4 + i][half*16 + col] = f2b(w);
          }
        } else {
#pragma unroll
          for (int i = 0; i < 4; ++i) pst[wave][quad*4 + i][half*16 + col] = 0;
        }
      }
      short8 pa = *(const short8*)&pst[wave][col][quad*8];
#pragma unroll
      for (int nt = 0; nt < 4; ++nt) {
        short8 bv = *(const short8*)&vsT[nt*16 + col][kc*32 + quad*8];
        oc[nt] = __builtin_amdgcn_mfma_f32_16x16x32_bf16(pa, bv, oc[nt], 0, 0, 0);
      }
    }

    // ---- store O[b, qn, h*64 + d] ----
#pragma unroll
    for (int nt = 0; nt < 4; ++nt)
#pragma unroll
      for (int i = 0; i < 4; ++i) {
        int qn = t*16 + quad*4 + i;
        if (qn <= 320)
          O[((size_t)(b*NQ + qn))*CDIM + h*HD + nt*16 + col] = f2b(oc[nt][i]);
      }
  }
}

extern "C" void kernel_launch(void* const* d_in, const int* in_sizes, int n_in,
                              void* d_out, int out_size, void* d_ws, size_t ws_size,
                              hipStream_t stream) {
  const float* x      = (const float*)d_in[0];
  const float* qkv_w  = (const float*)d_in[2];
  const float* qkv_b  = (const float*)d_in[3];
  const float* proj_w = (const float*)d_in[4];
  const float* proj_b = (const float*)d_in[5];
  const float* dp1_w  = (const float*)d_in[6];
  const float* dp1_b  = (const float*)d_in[7];
  const float* dp2_w  = (const float*)d_in[8];
  const float* dp2_b  = (const float*)d_in[9];
  const float* dp3_w  = (const float*)d_in[10];
  const float* dp3_b  = (const float*)d_in[11];
  float* out = (float*)d_out;

  char* ws = (char*)d_ws;
  size_t off = 0;
  auto alloc = [&](size_t bytes) -> void* {
    void* p = ws + off;
    off += (bytes + 255) & ~(size_t)255;
    return p;
  };
  u16*  xb      = (u16*)alloc((size_t)MQ * CDIM * 2);       // 37.8 MB
  u16*  qkv_wb  = (u16*)alloc((size_t)2304 * CDIM * 2);     // 3.5 MB
  u16*  proj_wb = (u16*)alloc((size_t)CDIM * CDIM * 2);     // 1.2 MB
  u16*  qkvb    = (u16*)alloc((size_t)MQ * 2304 * 2);       // 113.5 MB
  u16*  Obuf    = (u16*)alloc((size_t)MP * CDIM * 2);       // 31.6 MB
  float* tgt    = (float*)alloc((size_t)B_ * CDIM * 4);
  float* h1     = (float*)alloc((size_t)MD * 384 * 4);      // 25.2 MB
  float* h2     = (float*)alloc((size_t)MD * 192 * 4);      // 12.6 MB
  float* sdec   = (float*)alloc((size_t)MD * 4);
  // total ~226 MB

  // converts
  {
    int n4 = MQ * CDIM / 4;
    k_convert4<<<dim3((n4 + 255)/256), dim3(256), 0, stream>>>((const float4*)x, (ushort4*)xb, n4);
  }
  {
    int n4 = 2304 * CDIM / 4;
    k_convert4<<<dim3((n4 + 255)/256), dim3(256), 0, stream>>>((const float4*)qkv_w, (ushort4*)qkv_wb, n4);
  }
  {
    int n4 = CDIM * CDIM / 4;
    k_convert4<<<dim3((n4 + 255)/256), dim3(256), 0, stream>>>((const float4*)proj_w, (ushort4*)proj_wb, n4);
  }
  k_tgt<<<dim3(B_), dim3(CDIM), 0, stream>>>(x, tgt);

  // qkv = x @ qkv_w.T + qkv_b  (bf16 out) — 128x128 MFMA tile GEMM
  k_gemm128<<<dim3(2304/128, (MQ + 127)/128), dim3(256), 0, stream>>>(xb, qkv_wb, qkv_b, qkvb, (float*)nullptr,
                                                                      MQ, 2304, CDIM, 0);
  // decision path (fp32)
  k_gemm_f32<<<dim3(384/64, MD/64), dim3(16,16), 0, stream>>>(nullptr, x, tgt, dp1_w, dp1_b, h1,
                                                              MD, 384, 1536, 1);
  k_gemm_f32<<<dim3(192/64, MD/64), dim3(16,16), 0, stream>>>(h1, nullptr, nullptr, dp2_w, dp2_b, h2,
                                                              MD, 192, 384, 0);
  k_decision<<<dim3(MD/256), dim3(256), 0, stream>>>(h2, dp3_w, dp3_b, sdec);

  // attention
  k_attn<<<dim3(B_, NH), dim3(256), 0, stream>>>(qkvb, sdec, Obuf);

  // out = O @ proj_w.T + proj_b (fp32 out) — 128x128 MFMA tile GEMM
  k_gemm128<<<dim3(CDIM/128, (MP + 127)/128), dim3(256), 0, stream>>>(Obuf, proj_wb, proj_b, (u16*)nullptr, out,
                                                                      MP, CDIM, CDIM, 1);
}

// Round 3
// 900.725 us; speedup vs baseline: 2.3662x; 1.0566x over previous
//
#include <hip/hip_runtime.h>
#include <cmath>

typedef unsigned short u16;
typedef unsigned int u32;
typedef __attribute__((ext_vector_type(8))) short short8;
typedef __attribute__((ext_vector_type(4))) float f32x4;

#define B_    64
#define NV    385
#define CDIM  768
#define NQ    321
#define SFL   256
#define NH    12
#define HD    64
#define MQ    (B_*NV)   /* 24640 */
#define MP    (B_*NQ)   /* 20544 */
#define MD    (B_*SFL)  /* 16384 */
#define SCALE_ 0.125f
#define EPS_   1e-6f

__device__ __forceinline__ u16 f2b(float f) {
  u32 x = __float_as_uint(f);
  return (u16)((x + 0x7FFFu + ((x >> 16) & 1u)) >> 16);
}

__device__ __forceinline__ void gload_lds16(const void* g, void* l) {
  __builtin_amdgcn_global_load_lds(
      (const __attribute__((address_space(1))) u32*)g,
      (__attribute__((address_space(3))) u32*)l,
      16, 0, 0);
}

// ---------------- fp32 -> bf16 convert (vectorized) ----------------
__global__ void k_convert4(const float4* __restrict__ in, ushort4* __restrict__ out, int n4) {
  int i = blockIdx.x * blockDim.x + threadIdx.x;
  if (i < n4) {
    float4 v = in[i];
    ushort4 o;
    o.x = f2b(v.x); o.y = f2b(v.y); o.z = f2b(v.z); o.w = f2b(v.w);
    out[i] = o;
  }
}

// ---------------- tgt_rep = mean over x[:, 65:129, :] ----------------
__global__ void k_tgt(const float* __restrict__ x, float* __restrict__ tgt) {
  int b = blockIdx.x, c = threadIdx.x; // block = 768 threads
  float s = 0.f;
  for (int j = 0; j < 64; ++j) s += x[((size_t)(b*NV + 65 + j))*CDIM + c];
  tgt[b*CDIM + c] = s * (1.f/64.f);
}

// ---------------- m97-style 128x128 bf16 MFMA GEMM ----------------
__global__ __launch_bounds__(256) void k_gemm128(const u16* __restrict__ A, const u16* __restrict__ W,
                                                 const float* __restrict__ bias,
                                                 u16* __restrict__ Cb, float* __restrict__ Cf,
                                                 int M, int N, int K, int mode) {
  __shared__ __align__(16) u16 As[128*32];   // [row][k], contiguous (global_load_lds: no padding)
  __shared__ __align__(16) u16 Ws[128*32];
  int tid = threadIdx.x;
  int wave = tid >> 6, lane = tid & 63;
  int quad = lane >> 4, col = lane & 15;
  int m0 = blockIdx.y * 128, n0 = blockIdx.x * 128;

  int c0 = tid, c1 = 256 + tid;
  int ra0 = min(m0 + (c0 >> 2), M - 1), ra1 = min(m0 + (c1 >> 2), M - 1);
  int rb0 = n0 + (c0 >> 2),             rb1 = n0 + (c1 >> 2);
  const u16* pa0 = A + (size_t)ra0 * K + (c0 & 3) * 8;
  const u16* pa1 = A + (size_t)ra1 * K + (c1 & 3) * 8;
  const u16* pb0 = W + (size_t)rb0 * K + (c0 & 3) * 8;
  const u16* pb1 = W + (size_t)rb1 * K + (c1 & 3) * 8;
  u16* la0 = &As[(wave * 64) * 8];
  u16* la1 = &As[(256 + wave * 64) * 8];
  u16* lb0 = &Ws[(wave * 64) * 8];
  u16* lb1 = &Ws[(256 + wave * 64) * 8];

  int wm = (wave >> 1) * 64, wn = (wave & 1) * 64;
  f32x4 acc[4][4];
  f32x4 z4 = {0.f, 0.f, 0.f, 0.f};
#pragma unroll
  for (int i = 0; i < 4; ++i)
#pragma unroll
    for (int j = 0; j < 4; ++j) acc[i][j] = z4;

  for (int k0 = 0; k0 < K; k0 += 32) {
    gload_lds16(pa0, la0); gload_lds16(pa1, la1);
    gload_lds16(pb0, lb0); gload_lds16(pb1, lb1);
    pa0 += 32; pa1 += 32; pb0 += 32; pb1 += 32;
    __syncthreads();

    short8 af[4], bf[4];
#pragma unroll
    for (int i = 0; i < 4; ++i) af[i] = *(const short8*)&As[(wm + i*16 + col) * 32 + quad * 8];
#pragma unroll
    for (int j = 0; j < 4; ++j) bf[j] = *(const short8*)&Ws[(wn + j*16 + col) * 32 + quad * 8];
#pragma unroll
    for (int i = 0; i < 4; ++i)
#pragma unroll
      for (int j = 0; j < 4; ++j)
        acc[i][j] = __builtin_amdgcn_mfma_f32_16x16x32_bf16(af[i], bf[j], acc[i][j], 0, 0, 0);
    __syncthreads();
  }

#pragma unroll
  for (int j = 0; j < 4; ++j) {
    int cc = n0 + wn + j*16 + col;
    float bv = bias ? bias[cc] : 0.f;
#pragma unroll
    for (int i = 0; i < 4; ++i) {
      int r = m0 + wm + i*16 + quad*4;
#pragma unroll
      for (int ii = 0; ii < 4; ++ii) {
        if (r + ii < M) {
          float v = acc[i][j][ii] + bv;
          size_t off = (size_t)(r + ii) * N + cc;
          if (mode == 0) Cb[off] = f2b(v);
          else           Cf[off] = v;
        }
      }
    }
  }
}

// ---------------- fp32 GEMM v2 (decision path stays fp32) ----------------
// BM=128, BN=64, BK=16, block 256 (tx=tid&15 -> 4 n-cols, ty=tid>>4 -> 8 m-rows).
// LDS row strides 132 / 68 (st%8==4 -> transpose-writes are 2-way = free).
// gather=1: A row m -> x[b, 129+(m&255)], cols k0.. (K must be 768).
// bias2d=1: bias[(row>>8)*N + n] (per-batch bias, used for dp1 tgt-term).
__device__ __forceinline__ float gelu_exact(float x) {
  return 0.5f * x * (1.f + erff(x * 0.70710678118654752f));
}
__global__ __launch_bounds__(256) void k_gemm_f32(const float* __restrict__ A,
                                                  const float* __restrict__ x,
                                                  const float* __restrict__ W, int ldw,
                                                  const float* __restrict__ bias,
                                                  float* __restrict__ C, int M, int N, int K,
                                                  int gather, int gelu, int bias2d) {
  __shared__ __align__(16) float As[16][132];
  __shared__ __align__(16) float Ws[16][68];
  int tid = threadIdx.x;
  int tx = tid & 15, ty = tid >> 4;
  int n0 = blockIdx.x * 64, m0 = blockIdx.y * 128;
  float acc[8][4] = {};

  for (int k0 = 0; k0 < K; k0 += 16) {
    // stage A: 128x16, two passes of 256 float4
#pragma unroll
    for (int p = 0; p < 2; ++p) {
      int f = p * 256 + tid;
      int row = f >> 2, kc = (f & 3) * 4;
      float4 v;
      if (gather) {
        int m = m0 + row;
        int b = m >> 8, s2 = m & 255;
        v = *(const float4*)(x + ((size_t)(b*NV + 129 + s2))*CDIM + k0 + kc);
      } else {
        int m = min(m0 + row, M - 1);
        v = *(const float4*)(A + (size_t)m * K + k0 + kc);
      }
      As[kc+0][row] = v.x; As[kc+1][row] = v.y; As[kc+2][row] = v.z; As[kc+3][row] = v.w;
    }
    // stage W: 64x16, one pass (N assumed multiple of 64)
    {
      int row = tid >> 2, kc = (tid & 3) * 4;
      float4 wv = *(const float4*)(W + (size_t)(n0 + row) * ldw + k0 + kc);
      Ws[kc+0][row] = wv.x; Ws[kc+1][row] = wv.y; Ws[kc+2][row] = wv.z; Ws[kc+3][row] = wv.w;
    }
    __syncthreads();
#pragma unroll
    for (int k2 = 0; k2 < 16; ++k2) {
      float4 a0 = *(const float4*)&As[k2][ty*8];
      float4 a1 = *(const float4*)&As[k2][ty*8 + 4];
      float4 wv = *(const float4*)&Ws[k2][tx*4];
      float a_[8] = {a0.x, a0.y, a0.z, a0.w, a1.x, a1.y, a1.z, a1.w};
      float w_[4] = {wv.x, wv.y, wv.z, wv.w};
#pragma unroll
      for (int i = 0; i < 8; ++i)
#pragma unroll
        for (int j = 0; j < 4; ++j) acc[i][j] += a_[i] * w_[j];
    }
    __syncthreads();
  }
#pragma unroll
  for (int i = 0; i < 8; ++i) {
    int r = m0 + ty*8 + i;
    if (r < M) {
      float4 o;
      float* op = (float*)&o;
#pragma unroll
      for (int j = 0; j < 4; ++j) {
        int n = n0 + tx*4 + j;
        float bv = bias2d ? bias[(size_t)(r >> 8) * N + n] : bias[n];
        float v = acc[i][j] + bv;
        op[j] = gelu ? gelu_exact(v) : v;
      }
      *(float4*)(C + (size_t)r * N + n0 + tx*4) = o;
    }
  }
}

// ---------------- decision: argmax of (h2 @ dp3_w.T + dp3_b), fp32 ----------------
__global__ void k_decision(const float* __restrict__ h2, const float* __restrict__ w3,
                           const float* __restrict__ b3, float* __restrict__ sdec) {
  int r = blockIdx.x * blockDim.x + threadIdx.x; // 16384 rows
  const float* hp = h2 + (size_t)r * 192;
  float l0 = b3[0], l1 = b3[1];
  for (int k = 0; k < 192; ++k) { float h = hp[k]; l0 += h * w3[k]; l1 += h * w3[192 + k]; }
  sdec[r] = (l1 > l0) ? 1.f : 0.f; // jnp.argmax ties -> 0
}

// ---------------- attention: one block (256 thr / 4 waves) per (b, h) ----------------
__global__ __launch_bounds__(256) void k_attn(const u16* __restrict__ qkvb, const float* __restrict__ sdec,
                                              u16* __restrict__ O) {
  __shared__ __align__(16) u16 vsT[64][424];   // V^T: [d][key], stride 424 (2-way bank alias only)
  __shared__ float sd[256];
  __shared__ __align__(16) u16 pst[4][16][40]; // per-wave P staging, 16x32 used, stride 40
  int b = blockIdx.x, h = blockIdx.y;
  int tid = threadIdx.x;
  int wave = tid >> 6, lane = tid & 63;
  int quad = lane >> 4, col = lane & 15;

  sd[tid] = sdec[b*SFL + tid];
  for (int i = tid; i < 64*39; i += 256) {
    int d = i / 39, c = 385 + (i - d*39);
    vsT[d][c] = 0;
  }
  for (int idx = tid; idx < NV*8; idx += 256) {
    int n = idx >> 3, seg = idx & 7;
    const u16* src = qkvb + ((size_t)(b*NV + n))*2304 + 1536 + h*HD + seg*8;
    int d0 = seg*8;
#pragma unroll
    for (int j = 0; j < 8; ++j) vsT[d0 + j][n] = src[j];
  }
  __syncthreads();

  for (int t = wave; t < 21; t += 4) {
    int qn_a = t*16 + col;
    int pos = (qn_a == 0) ? 0 : (min(qn_a, 320) + 64);
    const u16* qp = qkvb + ((size_t)(b*NV + pos))*2304 + h*HD + quad*8;
    short8 aq0 = *(const short8*)(qp);
    short8 aq1 = *(const short8*)(qp + 32);

    f32x4 acc[25];
    f32x4 z4 = {0.f, 0.f, 0.f, 0.f};
#pragma unroll
    for (int kt = 0; kt < 25; ++kt) acc[kt] = z4;
#pragma unroll
    for (int kt = 0; kt < 25; ++kt) {
      int key = min(kt*16 + col, 384);
      const u16* kp = qkvb + ((size_t)(b*NV + key))*2304 + 768 + h*HD + quad*8;
      short8 b0 = *(const short8*)(kp);
      short8 b1 = *(const short8*)(kp + 32);
      acc[kt] = __builtin_amdgcn_mfma_f32_16x16x32_bf16(aq0, b0, acc[kt], 0, 0, 0);
      acc[kt] = __builtin_amdgcn_mfma_f32_16x16x32_bf16(aq1, b1, acc[kt], 0, 0, 0);
    }

    float inv[4];
#pragma unroll
    for (int i = 0; i < 4; ++i) {
      int qn = t*16 + quad*4 + i;
      bool rowTpl = (qn >= 1 && qn <= 64);
      bool rowSearch = (qn >= 65);
      float sdq = rowSearch ? sd[min(qn - 65, 255)] : 1.f;
      float mx = -1e30f;
#pragma unroll
      for (int kt = 0; kt < 25; ++kt) {
        int key = kt*16 + col;
        if (key <= 384) mx = fmaxf(mx, acc[kt][i]);
      }
#pragma unroll
      for (int m2 = 1; m2 <= 8; m2 <<= 1) mx = fmaxf(mx, __shfl_xor(mx, m2, 64));
      mx *= SCALE_;
      float sum = 0.f;
#pragma unroll
      for (int kt = 0; kt < 25; ++kt) {
        int key = kt*16 + col;
        float a = 0.f;
        if (key <= 384) {
          float msk = 1.f;
          if (rowTpl && key >= 129) msk = sd[key - 129];
          if (rowSearch && key >= 1 && key <= 128) msk = sdq;
          a = __expf(acc[kt][i] * SCALE_ - mx) * msk;
        }
        acc[kt][i] = a;
        sum += a;
      }
#pragma unroll
      for (int m2 = 1; m2 <= 8; m2 <<= 1) sum += __shfl_xor(sum, m2, 64);
      inv[i] = 1.f / (sum + EPS_);
    }

    f32x4 oc[4];
#pragma unroll
    for (int nt = 0; nt < 4; ++nt) oc[nt] = z4;
    const float epsn = EPS_ / 321.f;
#pragma unroll
    for (int kc = 0; kc < 13; ++kc) {
#pragma unroll
      for (int half = 0; half < 2; ++half) {
        int kt = kc*2 + half;
        if (kt < 25) {
#pragma unroll
          for (int i = 0; i < 4; ++i) {
            int key = kt*16 + col;
            float w = (key <= 384) ? (acc[kt][i] + epsn) * inv[i] : 0.f;
            pst[wave][quad*4 + i][half*16 + col] = f2b(w);
          }
        } else {
#pragma unroll
          for (int i = 0; i < 4; ++i) pst[wave][quad*4 + i][half*16 + col] = 0;
        }
      }
      short8 pa = *(const short8*)&pst[wave][col][quad*8];
#pragma unroll
      for (int nt = 0; nt < 4; ++nt) {
        short8 bv = *(const short8*)&vsT[nt*16 + col][kc*32 + quad*8];
        oc[nt] = __builtin_amdgcn_mfma_f32_16x16x32_bf16(pa, bv, oc[nt], 0, 0, 0);
      }
    }

#pragma unroll
    for (int nt = 0; nt < 4; ++nt)
#pragma unroll
      for (int i = 0; i < 4; ++i) {
        int qn = t*16 + quad*4 + i;
        if (qn <= 320)
          O[((size_t)(b*NQ + qn))*CDIM + h*HD + nt*16 + col] = f2b(oc[nt][i]);
      }
  }
}

extern "C" void kernel_launch(void* const* d_in, const int* in_sizes, int n_in,
                              void* d_out, int out_size, void* d_ws, size_t ws_size,
                              hipStream_t stream) {
  const float* x      = (const float*)d_in[0];
  const float* qkv_w  = (const float*)d_in[2];
  const float* qkv_b  = (const float*)d_in[3];
  const float* proj_w = (const float*)d_in[4];
  const float* proj_b = (const float*)d_in[5];
  const float* dp1_w  = (const float*)d_in[6];
  const float* dp1_b  = (const float*)d_in[7];
  const float* dp2_w  = (const float*)d_in[8];
  const float* dp2_b  = (const float*)d_in[9];
  const float* dp3_w  = (const float*)d_in[10];
  const float* dp3_b  = (const float*)d_in[11];
  float* out = (float*)d_out;

  char* ws = (char*)d_ws;
  size_t off = 0;
  auto alloc = [&](size_t bytes) -> void* {
    void* p = ws + off;
    off += (bytes + 255) & ~(size_t)255;
    return p;
  };
  u16*  xb      = (u16*)alloc((size_t)MQ * CDIM * 2);       // 37.8 MB
  u16*  qkv_wb  = (u16*)alloc((size_t)2304 * CDIM * 2);     // 3.5 MB
  u16*  proj_wb = (u16*)alloc((size_t)CDIM * CDIM * 2);     // 1.2 MB
  u16*  qkvb    = (u16*)alloc((size_t)MQ * 2304 * 2);       // 113.5 MB
  u16*  Obuf    = (u16*)alloc((size_t)MP * CDIM * 2);       // 31.6 MB
  float* tgt    = (float*)alloc((size_t)B_ * CDIM * 4);
  float* tb     = (float*)alloc((size_t)B_ * 384 * 4);      // per-batch dp1 tgt-term bias
  float* h1     = (float*)alloc((size_t)MD * 384 * 4);      // 25.2 MB
  float* h2     = (float*)alloc((size_t)MD * 192 * 4);      // 12.6 MB
  float* sdec   = (float*)alloc((size_t)MD * 4);

  // converts
  {
    int n4 = MQ * CDIM / 4;
    k_convert4<<<dim3((n4 + 255)/256), dim3(256), 0, stream>>>((const float4*)x, (ushort4*)xb, n4);
  }
  {
    int n4 = 2304 * CDIM / 4;
    k_convert4<<<dim3((n4 + 255)/256), dim3(256), 0, stream>>>((const float4*)qkv_w, (ushort4*)qkv_wb, n4);
  }
  {
    int n4 = CDIM * CDIM / 4;
    k_convert4<<<dim3((n4 + 255)/256), dim3(256), 0, stream>>>((const float4*)proj_w, (ushort4*)proj_wb, n4);
  }
  k_tgt<<<dim3(B_), dim3(CDIM), 0, stream>>>(x, tgt);

  // qkv = x @ qkv_w.T + qkv_b  (bf16 out)
  k_gemm128<<<dim3(2304/128, (MQ + 127)/128), dim3(256), 0, stream>>>(xb, qkv_wb, qkv_b, qkvb, (float*)nullptr,
                                                                      MQ, 2304, CDIM, 0);
  // decision path (fp32):
  // tb[b,n] = dp1_b[n] + tgt[b] . dp1_w[n, 768:]   (M=64 tiny GEMM, no gelu)
  k_gemm_f32<<<dim3(384/64, 1), dim3(256), 0, stream>>>(tgt, nullptr, dp1_w + 768, 1536, dp1_b, tb,
                                                        B_, 384, CDIM, 0, 0, 0);
  // h1 = gelu(x_search @ dp1_w[:, :768].T + tb[b])  (K halved: tgt term folded into tb)
  k_gemm_f32<<<dim3(384/64, MD/128), dim3(256), 0, stream>>>(nullptr, x, dp1_w, 1536, tb, h1,
                                                             MD, 384, CDIM, 1, 1, 1);
  // h2 = gelu(h1 @ dp2_w.T + dp2_b)
  k_gemm_f32<<<dim3(192/64, MD/128), dim3(256), 0, stream>>>(h1, nullptr, dp2_w, 384, dp2_b, h2,
                                                             MD, 192, 384, 0, 1, 0);
  k_decision<<<dim3(MD/256), dim3(256), 0, stream>>>(h2, dp3_w, dp3_b, sdec);

  // attention
  k_attn<<<dim3(B_, NH), dim3(256), 0, stream>>>(qkvb, sdec, Obuf);

  // out = O @ proj_w.T + proj_b (fp32 out)
  k_gemm128<<<dim3(CDIM/128, (MP + 127)/128), dim3(256), 0, stream>>>(Obuf, proj_wb, proj_b, (u16*)nullptr, out,
                                                                      MP, CDIM, CDIM, 1);
}

// Round 4
// 843.019 us; speedup vs baseline: 2.5282x; 1.0685x over previous
//
#include <hip/hip_runtime.h>
#include <cmath>

typedef unsigned short u16;
typedef unsigned int u32;
typedef __attribute__((ext_vector_type(8))) short short8;
typedef __attribute__((ext_vector_type(4))) float f32x4;

#define B_    64
#define NV    385
#define CDIM  768
#define NQ    321
#define SFL   256
#define NH    12
#define HD    64
#define MQ    (B_*NV)   /* 24640 */
#define MP    (B_*NQ)   /* 20544 */
#define MD    (B_*SFL)  /* 16384 */
#define SCALE_ 0.125f
#define EPS_   1e-6f

__device__ __forceinline__ u16 f2b(float f) {
  u32 x = __float_as_uint(f);
  return (u16)((x + 0x7FFFu + ((x >> 16) & 1u)) >> 16);
}

__device__ __forceinline__ void gload_lds16(const void* g, void* l) {
  __builtin_amdgcn_global_load_lds(
      (const __attribute__((address_space(1))) u32*)g,
      (__attribute__((address_space(3))) u32*)l,
      16, 0, 0);
}

// ---------------- fp32 -> bf16 convert (vectorized) ----------------
__global__ void k_convert4(const float4* __restrict__ in, ushort4* __restrict__ out, int n4) {
  int i = blockIdx.x * blockDim.x + threadIdx.x;
  if (i < n4) {
    float4 v = in[i];
    ushort4 o;
    o.x = f2b(v.x); o.y = f2b(v.y); o.z = f2b(v.z); o.w = f2b(v.w);
    out[i] = o;
  }
}

// ---------------- tgt_rep = mean over x[:, 65:129, :] ----------------
__global__ void k_tgt(const float* __restrict__ x, float* __restrict__ tgt) {
  int b = blockIdx.x, c = threadIdx.x; // block = 768 threads
  float s = 0.f;
  for (int j = 0; j < 64; ++j) s += x[((size_t)(b*NV + 65 + j))*CDIM + c];
  tgt[b*CDIM + c] = s * (1.f/64.f);
}

// ---------------- 128x128 bf16 MFMA GEMM, BK=64, XOR-swizzled LDS ----------------
// C[m,n] = sum_k A[m,k]*W[n,k] + bias[n]. grid (N/128, ceil(M/128)), block 256.
// Staging via global_load_lds width=16; source-chunk XOR swizzle seg^=row&7 makes
// fragment ds_read_b128 conflict-free (un-swizzled on read). K % 64 == 0, N % 128 == 0.
// mode 0 -> bf16 out (LDS-staged 256B-row coalesced stores), 1 -> f32 out (direct, 64B segs).
__global__ __launch_bounds__(256) void k_gemm128(const u16* __restrict__ A, const u16* __restrict__ W,
                                                 const float* __restrict__ bias,
                                                 u16* __restrict__ Cb, float* __restrict__ Cf,
                                                 int M, int N, int K, int mode) {
  __shared__ __align__(16) u16 sbuf[128*128];  // 32 KB: As=sbuf[0:8192), Ws=sbuf[8192:16384)
  u16* As = sbuf;
  u16* Ws = sbuf + 8192;
  int tid = threadIdx.x;
  int wave = tid >> 6, lane = tid & 63;
  int quad = lane >> 4, col = lane & 15;
  int m0 = blockIdx.y * 128, n0 = blockIdx.x * 128;

  // per-thread staging sources: 4 A-chunks + 4 W-chunks of 16 B per k-step
  const u16* pa[4];
  const u16* pb[4];
#pragma unroll
  for (int p = 0; p < 4; ++p) {
    int c = p*256 + tid;
    int row = c >> 3;
    int sg = (c & 7) ^ (row & 7);          // XOR swizzle (source-side)
    pa[p] = A + (size_t)min(m0 + row, M - 1) * K + sg*8;
    pb[p] = W + (size_t)(n0 + row) * K + sg*8;
  }

  int wm = (wave >> 1) * 64, wn = (wave & 1) * 64;
  f32x4 acc[4][4];
  f32x4 z4 = {0.f, 0.f, 0.f, 0.f};
#pragma unroll
  for (int i = 0; i < 4; ++i)
#pragma unroll
    for (int j = 0; j < 4; ++j) acc[i][j] = z4;

  for (int k0 = 0; k0 < K; k0 += 64) {
#pragma unroll
    for (int p = 0; p < 4; ++p) {
      gload_lds16(pa[p], &As[(p*256 + wave*64) * 8]);
      gload_lds16(pb[p], &Ws[(p*256 + wave*64) * 8]);
      pa[p] += 64; pb[p] += 64;
    }
    __syncthreads();

#pragma unroll
    for (int kk = 0; kk < 2; ++kk) {
      int sr = quad + kk*4;                // 16B chunk index within the 64-u16 row
      short8 af[4], bf[4];
#pragma unroll
      for (int i = 0; i < 4; ++i) {
        int row = wm + i*16 + col;
        af[i] = *(const short8*)&As[row*64 + ((sr ^ (row & 7)) * 8)];
      }
#pragma unroll
      for (int j = 0; j < 4; ++j) {
        int row = wn + j*16 + col;
        bf[j] = *(const short8*)&Ws[row*64 + ((sr ^ (row & 7)) * 8)];
      }
#pragma unroll
      for (int i = 0; i < 4; ++i)
#pragma unroll
        for (int j = 0; j < 4; ++j)
          acc[i][j] = __builtin_amdgcn_mfma_f32_16x16x32_bf16(af[i], bf[j], acc[i][j], 0, 0, 0);
    }
    __syncthreads();
  }

  if (mode == 0) {
    // stage C-tile (bf16) in sbuf[128][128], then 256B-contiguous row stores
#pragma unroll
    for (int j = 0; j < 4; ++j) {
      int cc = wn + j*16 + col;
      float bv = bias ? bias[n0 + cc] : 0.f;
#pragma unroll
      for (int i = 0; i < 4; ++i)
#pragma unroll
        for (int ii = 0; ii < 4; ++ii) {
          int row = wm + i*16 + quad*4 + ii;
          sbuf[row*128 + cc] = f2b(acc[i][j][ii] + bv);
        }
    }
    __syncthreads();
#pragma unroll
    for (int q = 0; q < 8; ++q) {
      int idx = q*256 + tid;
      int row = idx >> 4, c16 = idx & 15;
      if (m0 + row < M)
        *(float4*)(Cb + (size_t)(m0 + row) * N + n0 + c16*8) = *(const float4*)&sbuf[row*128 + c16*8];
    }
  } else {
    // fp32 out: direct stores (64-B aligned segments, coalesce fine)
#pragma unroll
    for (int j = 0; j < 4; ++j) {
      int cc = n0 + wn + j*16 + col;
      float bv = bias ? bias[cc] : 0.f;
#pragma unroll
      for (int i = 0; i < 4; ++i) {
        int r = m0 + wm + i*16 + quad*4;
#pragma unroll
        for (int ii = 0; ii < 4; ++ii) {
          if (r + ii < M) Cf[(size_t)(r + ii) * N + cc] = acc[i][j][ii] + bv;
        }
      }
    }
  }
}

// ---------------- fp32 GEMM v2 (decision path stays fp32) ----------------
__device__ __forceinline__ float gelu_exact(float x) {
  return 0.5f * x * (1.f + erff(x * 0.70710678118654752f));
}
__global__ __launch_bounds__(256) void k_gemm_f32(const float* __restrict__ A,
                                                  const float* __restrict__ x,
                                                  const float* __restrict__ W, int ldw,
                                                  const float* __restrict__ bias,
                                                  float* __restrict__ C, int M, int N, int K,
                                                  int gather, int gelu, int bias2d) {
  __shared__ __align__(16) float As[16][132];
  __shared__ __align__(16) float Ws[16][68];
  int tid = threadIdx.x;
  int tx = tid & 15, ty = tid >> 4;
  int n0 = blockIdx.x * 64, m0 = blockIdx.y * 128;
  float acc[8][4] = {};

  for (int k0 = 0; k0 < K; k0 += 16) {
#pragma unroll
    for (int p = 0; p < 2; ++p) {
      int f = p * 256 + tid;
      int row = f >> 2, kc = (f & 3) * 4;
      float4 v;
      if (gather) {
        int m = m0 + row;
        int b = m >> 8, s2 = m & 255;
        v = *(const float4*)(x + ((size_t)(b*NV + 129 + s2))*CDIM + k0 + kc);
      } else {
        int m = min(m0 + row, M - 1);
        v = *(const float4*)(A + (size_t)m * K + k0 + kc);
      }
      As[kc+0][row] = v.x; As[kc+1][row] = v.y; As[kc+2][row] = v.z; As[kc+3][row] = v.w;
    }
    {
      int row = tid >> 2, kc = (tid & 3) * 4;
      float4 wv = *(const float4*)(W + (size_t)(n0 + row) * ldw + k0 + kc);
      Ws[kc+0][row] = wv.x; Ws[kc+1][row] = wv.y; Ws[kc+2][row] = wv.z; Ws[kc+3][row] = wv.w;
    }
    __syncthreads();
#pragma unroll
    for (int k2 = 0; k2 < 16; ++k2) {
      float4 a0 = *(const float4*)&As[k2][ty*8];
      float4 a1 = *(const float4*)&As[k2][ty*8 + 4];
      float4 wv = *(const float4*)&Ws[k2][tx*4];
      float a_[8] = {a0.x, a0.y, a0.z, a0.w, a1.x, a1.y, a1.z, a1.w};
      float w_[4] = {wv.x, wv.y, wv.z, wv.w};
#pragma unroll
      for (int i = 0; i < 8; ++i)
#pragma unroll
        for (int j = 0; j < 4; ++j) acc[i][j] += a_[i] * w_[j];
    }
    __syncthreads();
  }
#pragma unroll
  for (int i = 0; i < 8; ++i) {
    int r = m0 + ty*8 + i;
    if (r < M) {
      float4 o;
      float* op = (float*)&o;
#pragma unroll
      for (int j = 0; j < 4; ++j) {
        int n = n0 + tx*4 + j;
        float bv = bias2d ? bias[(size_t)(r >> 8) * N + n] : bias[n];
        float v = acc[i][j] + bv;
        op[j] = gelu ? gelu_exact(v) : v;
      }
      *(float4*)(C + (size_t)r * N + n0 + tx*4) = o;
    }
  }
}

// ---------------- decision: argmax of (h2 @ dp3_w.T + dp3_b), fp32 ----------------
__global__ void k_decision(const float* __restrict__ h2, const float* __restrict__ w3,
                           const float* __restrict__ b3, float* __restrict__ sdec) {
  int r = blockIdx.x * blockDim.x + threadIdx.x; // 16384 rows
  const float* hp = h2 + (size_t)r * 192;
  float l0 = b3[0], l1 = b3[1];
  for (int k = 0; k < 192; ++k) { float h = hp[k]; l0 += h * w3[k]; l1 += h * w3[192 + k]; }
  sdec[r] = (l1 > l0) ? 1.f : 0.f; // jnp.argmax ties -> 0
}

// ---------------- attention: one block (256 thr / 4 waves) per (b, h) ----------------
__global__ __launch_bounds__(256) void k_attn(const u16* __restrict__ qkvb, const float* __restrict__ sdec,
                                              u16* __restrict__ O) {
  __shared__ __align__(16) u16 vsT[64][424];   // V^T: [d][key], stride 424 (2-way bank alias only)
  __shared__ float sd[256];
  __shared__ __align__(16) u16 pst[4][16][40]; // per-wave P staging, 16x32 used, stride 40
  int b = blockIdx.x, h = blockIdx.y;
  int tid = threadIdx.x;
  int wave = tid >> 6, lane = tid & 63;
  int quad = lane >> 4, col = lane & 15;

  sd[tid] = sdec[b*SFL + tid];
  for (int i = tid; i < 64*39; i += 256) {
    int d = i / 39, c = 385 + (i - d*39);
    vsT[d][c] = 0;
  }
  for (int idx = tid; idx < NV*8; idx += 256) {
    int n = idx >> 3, seg = idx & 7;
    const u16* src = qkvb + ((size_t)(b*NV + n))*2304 + 1536 + h*HD + seg*8;
    int d0 = seg*8;
#pragma unroll
    for (int j = 0; j < 8; ++j) vsT[d0 + j][n] = src[j];
  }
  __syncthreads();

  for (int t = wave; t < 21; t += 4) {
    int qn_a = t*16 + col;
    int pos = (qn_a == 0) ? 0 : (min(qn_a, 320) + 64);
    const u16* qp = qkvb + ((size_t)(b*NV + pos))*2304 + h*HD + quad*8;
    short8 aq0 = *(const short8*)(qp);
    short8 aq1 = *(const short8*)(qp + 32);

    f32x4 acc[25];
    f32x4 z4 = {0.f, 0.f, 0.f, 0.f};
#pragma unroll
    for (int kt = 0; kt < 25; ++kt) acc[kt] = z4;
#pragma unroll
    for (int kt = 0; kt < 25; ++kt) {
      int key = min(kt*16 + col, 384);
      const u16* kp = qkvb + ((size_t)(b*NV + key))*2304 + 768 + h*HD + quad*8;
      short8 b0 = *(const short8*)(kp);
      short8 b1 = *(const short8*)(kp + 32);
      acc[kt] = __builtin_amdgcn_mfma_f32_16x16x32_bf16(aq0, b0, acc[kt], 0, 0, 0);
      acc[kt] = __builtin_amdgcn_mfma_f32_16x16x32_bf16(aq1, b1, acc[kt], 0, 0, 0);
    }

    float inv[4];
#pragma unroll
    for (int i = 0; i < 4; ++i) {
      int qn = t*16 + quad*4 + i;
      bool rowTpl = (qn >= 1 && qn <= 64);
      bool rowSearch = (qn >= 65);
      float sdq = rowSearch ? sd[min(qn - 65, 255)] : 1.f;
      float mx = -1e30f;
#pragma unroll
      for (int kt = 0; kt < 25; ++kt) {
        int key = kt*16 + col;
        if (key <= 384) mx = fmaxf(mx, acc[kt][i]);
      }
#pragma unroll
      for (int m2 = 1; m2 <= 8; m2 <<= 1) mx = fmaxf(mx, __shfl_xor(mx, m2, 64));
      mx *= SCALE_;
      float sum = 0.f;
#pragma unroll
      for (int kt = 0; kt < 25; ++kt) {
        int key = kt*16 + col;
        float a = 0.f;
        if (key <= 384) {
          float msk = 1.f;
          if (rowTpl && key >= 129) msk = sd[key - 129];
          if (rowSearch && key >= 1 && key <= 128) msk = sdq;
          a = __expf(acc[kt][i] * SCALE_ - mx) * msk;
        }
        acc[kt][i] = a;
        sum += a;
      }
#pragma unroll
      for (int m2 = 1; m2 <= 8; m2 <<= 1) sum += __shfl_xor(sum, m2, 64);
      inv[i] = 1.f / (sum + EPS_);
    }

    f32x4 oc[4];
#pragma unroll
    for (int nt = 0; nt < 4; ++nt) oc[nt] = z4;
    const float epsn = EPS_ / 321.f;
#pragma unroll
    for (int kc = 0; kc < 13; ++kc) {
#pragma unroll
      for (int half = 0; half < 2; ++half) {
        int kt = kc*2 + half;
        if (kt < 25) {
#pragma unroll
          for (int i = 0; i < 4; ++i) {
            int key = kt*16 + col;
            float w = (key <= 384) ? (acc[kt][i] + epsn) * inv[i] : 0.f;
            pst[wave][quad*4 + i][half*16 + col] = f2b(w);
          }
        } else {
#pragma unroll
          for (int i = 0; i < 4; ++i) pst[wave][quad*4 + i][half*16 + col] = 0;
        }
      }
      short8 pa = *(const short8*)&pst[wave][col][quad*8];
#pragma unroll
      for (int nt = 0; nt < 4; ++nt) {
        short8 bv = *(const short8*)&vsT[nt*16 + col][kc*32 + quad*8];
        oc[nt] = __builtin_amdgcn_mfma_f32_16x16x32_bf16(pa, bv, oc[nt], 0, 0, 0);
      }
    }

#pragma unroll
    for (int nt = 0; nt < 4; ++nt)
#pragma unroll
      for (int i = 0; i < 4; ++i) {
        int qn = t*16 + quad*4 + i;
        if (qn <= 320)
          O[((size_t)(b*NQ + qn))*CDIM + h*HD + nt*16 + col] = f2b(oc[nt][i]);
      }
  }
}

extern "C" void kernel_launch(void* const* d_in, const int* in_sizes, int n_in,
                              void* d_out, int out_size, void* d_ws, size_t ws_size,
                              hipStream_t stream) {
  const float* x      = (const float*)d_in[0];
  const float* qkv_w  = (const float*)d_in[2];
  const float* qkv_b  = (const float*)d_in[3];
  const float* proj_w = (const float*)d_in[4];
  const float* proj_b = (const float*)d_in[5];
  const float* dp1_w  = (const float*)d_in[6];
  const float* dp1_b  = (const float*)d_in[7];
  const float* dp2_w  = (const float*)d_in[8];
  const float* dp2_b  = (const float*)d_in[9];
  const float* dp3_w  = (const float*)d_in[10];
  const float* dp3_b  = (const float*)d_in[11];
  float* out = (float*)d_out;

  char* ws = (char*)d_ws;
  size_t off = 0;
  auto alloc = [&](size_t bytes) -> void* {
    void* p = ws + off;
    off += (bytes + 255) & ~(size_t)255;
    return p;
  };
  u16*  xb      = (u16*)alloc((size_t)MQ * CDIM * 2);       // 37.8 MB
  u16*  qkv_wb  = (u16*)alloc((size_t)2304 * CDIM * 2);     // 3.5 MB
  u16*  proj_wb = (u16*)alloc((size_t)CDIM * CDIM * 2);     // 1.2 MB
  u16*  qkvb    = (u16*)alloc((size_t)MQ * 2304 * 2);       // 113.5 MB
  u16*  Obuf    = (u16*)alloc((size_t)MP * CDIM * 2);       // 31.6 MB
  float* tgt    = (float*)alloc((size_t)B_ * CDIM * 4);
  float* tb     = (float*)alloc((size_t)B_ * 384 * 4);      // per-batch dp1 tgt-term bias
  float* h1     = (float*)alloc((size_t)MD * 384 * 4);      // 25.2 MB
  float* h2     = (float*)alloc((size_t)MD * 192 * 4);      // 12.6 MB
  float* sdec   = (float*)alloc((size_t)MD * 4);

  // converts
  {
    int n4 = MQ * CDIM / 4;
    k_convert4<<<dim3((n4 + 255)/256), dim3(256), 0, stream>>>((const float4*)x, (ushort4*)xb, n4);
  }
  {
    int n4 = 2304 * CDIM / 4;
    k_convert4<<<dim3((n4 + 255)/256), dim3(256), 0, stream>>>((const float4*)qkv_w, (ushort4*)qkv_wb, n4);
  }
  {
    int n4 = CDIM * CDIM / 4;
    k_convert4<<<dim3((n4 + 255)/256), dim3(256), 0, stream>>>((const float4*)proj_w, (ushort4*)proj_wb, n4);
  }
  k_tgt<<<dim3(B_), dim3(CDIM), 0, stream>>>(x, tgt);

  // qkv = x @ qkv_w.T + qkv_b  (bf16 out)
  k_gemm128<<<dim3(2304/128, (MQ + 127)/128), dim3(256), 0, stream>>>(xb, qkv_wb, qkv_b, qkvb, (float*)nullptr,
                                                                      MQ, 2304, CDIM, 0);
  // decision path (fp32):
  k_gemm_f32<<<dim3(384/64, 1), dim3(256), 0, stream>>>(tgt, nullptr, dp1_w + 768, 1536, dp1_b, tb,
                                                        B_, 384, CDIM, 0, 0, 0);
  k_gemm_f32<<<dim3(384/64, MD/128), dim3(256), 0, stream>>>(nullptr, x, dp1_w, 1536, tb, h1,
                                                             MD, 384, CDIM, 1, 1, 1);
  k_gemm_f32<<<dim3(192/64, MD/128), dim3(256), 0, stream>>>(h1, nullptr, dp2_w, 384, dp2_b, h2,
                                                             MD, 192, 384, 0, 1, 0);
  k_decision<<<dim3(MD/256), dim3(256), 0, stream>>>(h2, dp3_w, dp3_b, sdec);

  // attention
  k_attn<<<dim3(B_, NH), dim3(256), 0, stream>>>(qkvb, sdec, Obuf);

  // out = O @ proj_w.T + proj_b (fp32 out)
  k_gemm128<<<dim3(CDIM/128, (MP + 127)/128), dim3(256), 0, stream>>>(Obuf, proj_wb, proj_b, (u16*)nullptr, out,
                                                                      MP, CDIM, CDIM, 1);
}